// Round 2
// baseline (1020.747 us; speedup 1.0000x reference)
//
#include <hip/hip_runtime.h>

// PRNNLayer: B=4096 chains x T=2048 steps, 5 states.
// R4: state-parallel role decomposition. Block = 256 threads = 4 waves on the
// 4 SIMDs of one CU; wave r handles role r for 64 chains:
//   role0: s0 (3 trans/step)   role1: s1+s3 (6 trans/step, critical)
//   role2: s2 (4 trans/step)   role3: s4 (4 trans/step)
// Per-step trans work per SIMD drops 17 -> 6. Inputs {pe,psnow,dm,day,da} come
// from a fully-parallel pre pass staged through OUT-as-scratch; per-chunk
// __syncthreads orders scratch reads (epoch k) before output overwrites
// (epoch k+1). All state formulas verbatim from the R3 kernel (verified).

#define NB 4096
#define NT 2048
#define CHUNK 8
#define NCHUNK (NT / CHUNK)  // 256

#define L2E10 14.4269504089f  // 10*log2(e)  (hv(x) = sigmoid(10x))
#define L2E    1.44269504089f

__device__ __forceinline__ float rcpf(float x) { return __builtin_amdgcn_rcpf(x); }
__device__ __forceinline__ float ex2(float a)  { return __builtin_amdgcn_exp2f(a); }
__device__ __forceinline__ float ex2c(float a) { return __builtin_amdgcn_exp2f(fminf(a, 80.0f)); }
__device__ __forceinline__ float clip1e5(float x) {
    return __builtin_amdgcn_fmed3f(x, -100000.0f, 100000.0f);
}

// ---------------- Pass 1: input-only work, 1 element/thread -----------------
// Writes {pe, psnow, dm, day, da} into OUT slots 0..4 (scratch for pass 2).
// Dense per-wave scalar loads/stores (no 80B-stride float4s).
__global__ __launch_bounds__(256)
void pre_kernel(const float* __restrict__ inp, const float* __restrict__ theta,
                float* __restrict__ out) {
    const float tmin_ = theta[4] * -3.0f;
    const float tmax_ = theta[5] * 3.0f;
    const float c_sn  = -L2E10 * tmin_;
    const float c_m   =  L2E10 * tmax_;

    const size_t k = (size_t)blockIdx.x * 256 + threadIdx.x;
    const float p  = inp[k * 3 + 0];
    const float tm = inp[k * 3 + 1];
    const float dl = inp[k * 3 + 2];

    const float A1 = tm + 237.3f;
    const float A2 = tm + 273.2f;
    const float q  = rcpf(A1 * A2);
    const float pe = 436.98672f * dl * ex2(24.958624f * tm * (q * A2)) * (q * A1);
    const float day   = rcpf(1.0f + ex2(fmaf(-L2E10, dl, 7.21347520f)));
    const float psnow = rcpf(1.0f + ex2(fmaf(L2E10, tm, c_sn))) * p;
    const float dm = 1.0f + ex2(fmaf(-L2E10, tm, c_m));  // 1+em
    const float da = 1.0f + ex2(fmaf(-L2E10, p, L2E));   // 1+ea

    float* o = out + k * 5;
    o[0] = pe; o[1] = psnow; o[2] = dm; o[3] = day; o[4] = da;
}

// ---------------- Pass 2: role-decomposed serial scan -----------------------
__global__ __launch_bounds__(256, 1)
void prnn_kernel(const float* __restrict__ inp, const float* __restrict__ theta,
                 float* __restrict__ out) {
    const int lane = threadIdx.x & 63;
    const int role = threadIdx.x >> 6;
    const int b = blockIdx.x * 64 + lane;

    // ---- theta (uniform); each role uses a subset, rest is DCE'd ----
    const float f_     = theta[0] * 0.1f;
    const float smax_  = theta[1] * 1950.0f;
    const float qmax_  = theta[2] * 50.0f;
    const float ddf_   = theta[3] * 5.0f;
    const float tmax_  = theta[5] * 3.0f;
    const float Kc_    = theta[6] * 0.5f;
    const float SCmax_ = theta[7] * 1.5f;
    const float spmax_ = theta[8] * 1950.0f;
    const float qpmax_ = theta[9] * 40.0f;
    const float kp     = theta[10];
    const float sgmax_ = theta[11] * 1950.0f;
    const float qgmax_ = theta[12] * 40.0f;
    const float Kl_    = theta[13] * 0.5f;
    const float Kn_    = theta[14] * 0.5f;

    const float inv_smax = rcpf(smax_);
    const float KcDc  = Kc_ * 0.849932f;
    const float c_dd  = -ddf_ * tmax_;
    const float c_sc1 =  L2E10 * SCmax_ * 1.4f;
    const float c_sc0 =  L2E10 * SCmax_ * 0.6f;
    const float c_2p  =  L2E10 * spmax_;
    const float c_3s  =  L2E10 * smax_;
    const float c_4s  =  L2E10 * sgmax_;
    const float fE    = f_ * L2E;
    const float c_E2  = -fE * spmax_;
    const float c_E3  = -fE * smax_;
    const float c_E4  = -fE * sgmax_;

    const float* ip = inp + (size_t)b * (NT * 3);
    float*       op = out + (size_t)b * (NT * 5);

    if (role == 0) {
        // ---- s0: e0, esc, Rp = 3 trans/step ----
        float s0 = 0.f;
        float pA[CHUNK], dyA[CHUNK], daA[CHUNK];
        float pB[CHUNK], dyB[CHUNK], daB[CHUNK];
        auto pf = [&](float* P, float* DY, float* DA, int c) {
            #pragma unroll
            for (int i = 0; i < CHUNK; ++i) {
                const int t = c * CHUNK + i;
                P[i]  = ip[t * 3 + 0];
                DY[i] = op[t * 5 + 3];
                DA[i] = op[t * 5 + 4];
            }
        };
        auto cw = [&](const float* P, const float* DY, const float* DA, int c) {
            #pragma unroll
            for (int i = 0; i < CHUNK; ++i) {
                const float p = P[i], day = DY[i], da = DA[i];
                const float lai   = fmaf(0.328f, day, 0.15f);
                const float kcf   = fmaf(0.6f, day, 0.4f);
                const float kterm = KcDc * kcf * lai;
                const float zday  = fmaf(c_sc1, day, c_sc0);
                const float e0  = ex2(-L2E10 * s0);
                const float esc = ex2(fmaf(-L2E10, s0, zday));
                const float d0  = 1.0f + e0;
                const float dsc = 1.0f + esc;
                const float Rp  = rcpf(da * d0 * dsc);
                const float pintc = Rp * fmaf(d0 * esc, kterm, p);
                s0 += clip1e5(pintc);
                op[(c * CHUNK + i) * 5 + 0] = s0;
            }
        };
        pf(pA, dyA, daA, 0);
        __syncthreads();
        for (int c = 0; c < NCHUNK; c += 2) {
            pf(pB, dyB, daB, c + 1);
            cw(pA, dyA, daA, c);
            __syncthreads();
            if (c + 2 < NCHUNK) pf(pA, dyA, daA, c + 2);
            cw(pB, dyB, daB, c + 1);
            __syncthreads();
        }
    } else if (role == 1) {
        // ---- s1 + s3 (critical role): 4 exp2 + 2 rcp per step ----
        float s1 = 0.f, s3 = 0.f;
        float pA[CHUNK], tA[CHUNK], peA[CHUNK], psA[CHUNK], dmA[CHUNK];
        float pB[CHUNK], tB[CHUNK], peB[CHUNK], psB[CHUNK], dmB[CHUNK];
        auto pf = [&](float* P, float* TM, float* PE, float* PS, float* DM, int c) {
            #pragma unroll
            for (int i = 0; i < CHUNK; ++i) {
                const int t = c * CHUNK + i;
                P[i]  = ip[t * 3 + 0];
                TM[i] = ip[t * 3 + 1];
                PE[i] = op[t * 5 + 0];
                PS[i] = op[t * 5 + 1];
                DM[i] = op[t * 5 + 2];
            }
        };
        auto cw = [&](const float* P, const float* TM, const float* PE,
                      const float* PS, const float* DM, int c) {
            #pragma unroll
            for (int i = 0; i < CHUNK; ++i) {
                const float p = P[i], tm = TM[i], pe = PE[i];
                const float psnow = PS[i], dm = DM[i];
                const float prain = p - psnow;
                const float e1 = ex2(-L2E10 * s1);
                const float melt = rcpf(dm * (1.0f + e1))
                                   * fminf(s1, fmaf(ddf_, tm, c_dd));
                const float e3  = ex2(-L2E10 * s3);
                const float e3s = ex2c(fmaf(-L2E10, s3, c_3s));
                const float R3  = rcpf((1.0f + e3) * (1.0f + e3s));
                const float E3  = ex2(fmaf(fE, s3, c_E3));
                const float t_et = pe * fmaf(e3s * s3, inv_smax, 1.0f);
                const float t_qs = qmax_ * fmaf(e3s, E3, 1.0f);
                const float outflux = R3 * (t_et + t_qs + (s3 - smax_));
                const float ds3 = prain + melt - outflux;
                s1 += clip1e5(psnow - melt);
                s3 += clip1e5(ds3);
                const int t = c * CHUNK + i;
                op[t * 5 + 1] = s1;
                op[t * 5 + 3] = s3;
            }
        };
        pf(pA, tA, peA, psA, dmA, 0);
        __syncthreads();
        for (int c = 0; c < NCHUNK; c += 2) {
            pf(pB, tB, peB, psB, dmB, c + 1);
            cw(pA, tA, peA, psA, dmA, c);
            __syncthreads();
            if (c + 2 < NCHUNK) pf(pA, tA, peA, psA, dmA, c + 2);
            cw(pB, tB, peB, psB, dmB, c + 1);
            __syncthreads();
        }
    } else if (role == 2) {
        // ---- s2: 3 exp2 + 1 rcp per step ----
        float s2 = 0.f;
        float pA[CHUNK], pB[CHUNK];
        auto pf = [&](float* P, int c) {
            #pragma unroll
            for (int i = 0; i < CHUNK; ++i) P[i] = ip[(c * CHUNK + i) * 3 + 0];
        };
        auto cw = [&](const float* P, int c) {
            #pragma unroll
            for (int i = 0; i < CHUNK; ++i) {
                const float p = P[i];
                const float e2  = ex2(-L2E10 * s2);
                const float e2p = ex2c(fmaf(-L2E10, s2, c_2p));
                const float R2  = rcpf((1.0f + e2) * (1.0f + e2p));
                const float E2  = ex2(fmaf(fE, s2, c_E2));
                const float qpref = R2 * fmaf(e2p * E2, kp * p, qpmax_);
                s2 += clip1e5(qpref);
                op[(c * CHUNK + i) * 5 + 2] = s2;
            }
        };
        pf(pA, 0);
        __syncthreads();
        for (int c = 0; c < NCHUNK; c += 2) {
            pf(pB, c + 1);
            cw(pA, c);
            __syncthreads();
            if (c + 2 < NCHUNK) pf(pA, c + 2);
            cw(pB, c + 1);
            __syncthreads();
        }
    } else {
        // ---- s4: 3 exp2 + 1 rcp per step ----
        float s4 = 0.f;
        float pA[CHUNK], pB[CHUNK];
        auto pf = [&](float* P, int c) {
            #pragma unroll
            for (int i = 0; i < CHUNK; ++i) P[i] = ip[(c * CHUNK + i) * 3 + 0];
        };
        auto cw = [&](const float* P, int c) {
            #pragma unroll
            for (int i = 0; i < CHUNK; ++i) {
                const float p = P[i];
                const float e4  = ex2(-L2E10 * s4);
                const float e4s = ex2c(fmaf(-L2E10, s4, c_4s));
                const float R4  = rcpf((1.0f + e4) * (1.0f + e4s));
                const float E4  = ex2(fmaf(fE, s4, c_E4));
                const float pl  = p * fmaf(p, Kn_, Kl_);
                const float qslow = R4 * fmaf(e4s * E4, pl, qgmax_);
                s4 += clip1e5(qslow);
                op[(c * CHUNK + i) * 5 + 4] = s4;
            }
        };
        pf(pA, 0);
        __syncthreads();
        for (int c = 0; c < NCHUNK; c += 2) {
            pf(pB, c + 1);
            cw(pA, c);
            __syncthreads();
            if (c + 2 < NCHUNK) pf(pA, c + 2);
            cw(pB, c + 1);
            __syncthreads();
        }
    }
}

extern "C" void kernel_launch(void* const* d_in, const int* in_sizes, int n_in,
                              void* d_out, int out_size, void* d_ws, size_t ws_size,
                              hipStream_t stream) {
    const float* inp   = (const float*)d_in[0];
    const float* theta = (const float*)d_in[1];
    float* out = (float*)d_out;
    pre_kernel<<<(NB * NT) / 256, 256, 0, stream>>>(inp, theta, out);
    prnn_kernel<<<NB / 64, 256, 0, stream>>>(inp, theta, out);
}

// Round 3
// 1002.938 us; speedup vs baseline: 1.0178x; 1.0178x over previous
//
#include <hip/hip_runtime.h>

// PRNNLayer: B=4096 chains x T=2048 steps, 5 states.
// R5: zero-communication role decomposition. One 256-thread block = 4 waves
// on the 4 SIMDs of one CU; wave r runs role r for the block's 64 chains:
//   role0: s0        role1: s1+s3 (critical)   role2: s2        role3: s4
// Each role recomputes its input-only terms (pe/psnow/dm/day/da) from inp --
// they are off the serial critical path (state->exp2->rcp->state chain) and
// hide under its latency. No pre-pass, no scratch, NO barriers (R4's 257
// __syncthreads + vmcnt(0) drains were the regression). Roles share a CU only
// so their partial-line output writes merge in the same L2.
// All state-update formulas verbatim from the verified R3/R4 kernels.

#define NB 4096
#define NT 2048
#define CHUNK 8
#define NCHUNK (NT / CHUNK)  // 256

#define L2E10 14.4269504089f  // 10*log2(e)  (hv(x) = sigmoid(10x))
#define L2E    1.44269504089f

__device__ __forceinline__ float rcpf(float x) { return __builtin_amdgcn_rcpf(x); }
__device__ __forceinline__ float ex2(float a)  { return __builtin_amdgcn_exp2f(a); }
__device__ __forceinline__ float ex2c(float a) { return __builtin_amdgcn_exp2f(fminf(a, 80.0f)); }
__device__ __forceinline__ float clip1e5(float x) {
    return __builtin_amdgcn_fmed3f(x, -100000.0f, 100000.0f);
}

__global__ __launch_bounds__(256, 1)
void prnn_kernel(const float* __restrict__ inp, const float* __restrict__ theta,
                 float* __restrict__ out) {
    const int lane = threadIdx.x & 63;
    const int role = threadIdx.x >> 6;
    const int b = blockIdx.x * 64 + lane;

    // ---- theta (uniform); each role uses a subset, rest is DCE'd ----
    const float f_     = theta[0] * 0.1f;
    const float smax_  = theta[1] * 1950.0f;
    const float qmax_  = theta[2] * 50.0f;
    const float ddf_   = theta[3] * 5.0f;
    const float tmin_  = theta[4] * -3.0f;
    const float tmax_  = theta[5] * 3.0f;
    const float Kc_    = theta[6] * 0.5f;
    const float SCmax_ = theta[7] * 1.5f;
    const float spmax_ = theta[8] * 1950.0f;
    const float qpmax_ = theta[9] * 40.0f;
    const float kp     = theta[10];
    const float sgmax_ = theta[11] * 1950.0f;
    const float qgmax_ = theta[12] * 40.0f;
    const float Kl_    = theta[13] * 0.5f;
    const float Kn_    = theta[14] * 0.5f;

    const float inv_smax = rcpf(smax_);
    const float KcDc  = Kc_ * 0.849932f;          // Kc_ * 0.986*0.862
    const float c_sn  = -L2E10 * tmin_;
    const float c_m   =  L2E10 * tmax_;
    const float c_dd  = -ddf_ * tmax_;
    const float c_sc1 =  L2E10 * SCmax_ * 1.4f;
    const float c_sc0 =  L2E10 * SCmax_ * 0.6f;
    const float c_2p  =  L2E10 * spmax_;
    const float c_3s  =  L2E10 * smax_;
    const float c_4s  =  L2E10 * sgmax_;
    const float fE    = f_ * L2E;
    const float c_E2  = -fE * spmax_;
    const float c_E3  = -fE * smax_;
    const float c_E4  = -fE * sgmax_;

    const float* ip = inp + (size_t)b * (NT * 3);
    float*       op = out + (size_t)b * (NT * 5);

    if (role == 0) {
        // ---- s0: day/da recomputed inline (input-only, off critical path) ----
        float s0 = 0.f;
        float bA[CHUNK * 3], bB[CHUNK * 3];
        auto pf = [&](float* d, int c) {
            const float4* s = (const float4*)(ip + (size_t)c * (CHUNK * 3));
            #pragma unroll
            for (int i = 0; i < (CHUNK * 3) / 4; ++i) ((float4*)d)[i] = s[i];
        };
        auto cw = [&](const float* d, int c) {
            #pragma unroll
            for (int i = 0; i < CHUNK; ++i) {
                const float p  = d[i * 3 + 0];
                const float dl = d[i * 3 + 2];
                const float day = rcpf(1.0f + ex2(fmaf(-L2E10, dl, 7.21347520f)));
                const float da  = 1.0f + ex2(fmaf(-L2E10, p, L2E));
                const float lai   = fmaf(0.328f, day, 0.15f);
                const float kcf   = fmaf(0.6f, day, 0.4f);
                const float kterm = KcDc * kcf * lai;
                const float zday  = fmaf(c_sc1, day, c_sc0);
                const float e0  = ex2(-L2E10 * s0);
                const float esc = ex2(fmaf(-L2E10, s0, zday));
                const float d0  = 1.0f + e0;
                const float dsc = 1.0f + esc;
                const float Rp  = rcpf(da * d0 * dsc);
                const float pintc = Rp * fmaf(d0 * esc, kterm, p);
                s0 += clip1e5(pintc);
                op[(c * CHUNK + i) * 5 + 0] = s0;
            }
        };
        pf(bA, 0);
        for (int c = 0; c < NCHUNK; c += 2) {
            pf(bB, c + 1);
            cw(bA, c);
            if (c + 2 < NCHUNK) pf(bA, c + 2);
            cw(bB, c + 1);
        }
    } else if (role == 1) {
        // ---- s1 + s3 (critical role): pe/psnow/dm recomputed inline ----
        float s1 = 0.f, s3 = 0.f;
        float bA[CHUNK * 3], bB[CHUNK * 3];
        auto pf = [&](float* d, int c) {
            const float4* s = (const float4*)(ip + (size_t)c * (CHUNK * 3));
            #pragma unroll
            for (int i = 0; i < (CHUNK * 3) / 4; ++i) ((float4*)d)[i] = s[i];
        };
        auto cw = [&](const float* d, int c) {
            #pragma unroll
            for (int i = 0; i < CHUNK; ++i) {
                const float p  = d[i * 3 + 0];
                const float tm = d[i * 3 + 1];
                const float dl = d[i * 3 + 2];
                // input-only terms (verbatim)
                const float A1 = tm + 237.3f;
                const float A2 = tm + 273.2f;
                const float q  = rcpf(A1 * A2);
                const float pe = 436.98672f * dl * ex2(24.958624f * tm * (q * A2)) * (q * A1);
                const float psnow = rcpf(1.0f + ex2(fmaf(L2E10, tm, c_sn))) * p;
                const float dm = 1.0f + ex2(fmaf(-L2E10, tm, c_m));
                const float prain = p - psnow;
                // state-dependent (verbatim)
                const float e1 = ex2(-L2E10 * s1);
                const float melt = rcpf(dm * (1.0f + e1))
                                   * fminf(s1, fmaf(ddf_, tm, c_dd));
                const float e3  = ex2(-L2E10 * s3);
                const float e3s = ex2c(fmaf(-L2E10, s3, c_3s));
                const float R3  = rcpf((1.0f + e3) * (1.0f + e3s));
                const float E3  = ex2(fmaf(fE, s3, c_E3));
                const float t_et = pe * fmaf(e3s * s3, inv_smax, 1.0f);
                const float t_qs = qmax_ * fmaf(e3s, E3, 1.0f);
                const float outflux = R3 * (t_et + t_qs + (s3 - smax_));
                const float ds3 = prain + melt - outflux;
                s1 += clip1e5(psnow - melt);
                s3 += clip1e5(ds3);
                const int t = c * CHUNK + i;
                op[t * 5 + 1] = s1;
                op[t * 5 + 3] = s3;
            }
        };
        pf(bA, 0);
        for (int c = 0; c < NCHUNK; c += 2) {
            pf(bB, c + 1);
            cw(bA, c);
            if (c + 2 < NCHUNK) pf(bA, c + 2);
            cw(bB, c + 1);
        }
    } else if (role == 2) {
        // ---- s2: needs only p ----
        float s2 = 0.f;
        float pA[CHUNK], pB[CHUNK];
        auto pf = [&](float* P, int c) {
            #pragma unroll
            for (int i = 0; i < CHUNK; ++i) P[i] = ip[(c * CHUNK + i) * 3 + 0];
        };
        auto cw = [&](const float* P, int c) {
            #pragma unroll
            for (int i = 0; i < CHUNK; ++i) {
                const float p = P[i];
                const float e2  = ex2(-L2E10 * s2);
                const float e2p = ex2c(fmaf(-L2E10, s2, c_2p));
                const float R2  = rcpf((1.0f + e2) * (1.0f + e2p));
                const float E2  = ex2(fmaf(fE, s2, c_E2));
                const float qpref = R2 * fmaf(e2p * E2, kp * p, qpmax_);
                s2 += clip1e5(qpref);
                op[(c * CHUNK + i) * 5 + 2] = s2;
            }
        };
        pf(pA, 0);
        for (int c = 0; c < NCHUNK; c += 2) {
            pf(pB, c + 1);
            cw(pA, c);
            if (c + 2 < NCHUNK) pf(pA, c + 2);
            cw(pB, c + 1);
        }
    } else {
        // ---- s4: needs only p ----
        float s4 = 0.f;
        float pA[CHUNK], pB[CHUNK];
        auto pf = [&](float* P, int c) {
            #pragma unroll
            for (int i = 0; i < CHUNK; ++i) P[i] = ip[(c * CHUNK + i) * 3 + 0];
        };
        auto cw = [&](const float* P, int c) {
            #pragma unroll
            for (int i = 0; i < CHUNK; ++i) {
                const float p = P[i];
                const float e4  = ex2(-L2E10 * s4);
                const float e4s = ex2c(fmaf(-L2E10, s4, c_4s));
                const float R4  = rcpf((1.0f + e4) * (1.0f + e4s));
                const float E4  = ex2(fmaf(fE, s4, c_E4));
                const float pl  = p * fmaf(p, Kn_, Kl_);
                const float qslow = R4 * fmaf(e4s * E4, pl, qgmax_);
                s4 += clip1e5(qslow);
                op[(c * CHUNK + i) * 5 + 4] = s4;
            }
        };
        pf(pA, 0);
        for (int c = 0; c < NCHUNK; c += 2) {
            pf(pB, c + 1);
            cw(pA, c);
            if (c + 2 < NCHUNK) pf(pA, c + 2);
            cw(pB, c + 1);
        }
    }
}

extern "C" void kernel_launch(void* const* d_in, const int* in_sizes, int n_in,
                              void* d_out, int out_size, void* d_ws, size_t ws_size,
                              hipStream_t stream) {
    const float* inp   = (const float*)d_in[0];
    const float* theta = (const float*)d_in[1];
    float* out = (float*)d_out;
    prnn_kernel<<<NB / 64, 256, 0, stream>>>(inp, theta, out);
}

// Round 4
// 762.600 us; speedup vs baseline: 1.3385x; 1.3152x over previous
//
#include <hip/hip_runtime.h>

// PRNNLayer: B=4096 chains x T=2048 steps, 5 states.
// R6: role decomposition (R5) + SoA-plane stores to workspace + final
// transpose. R5's counters showed 3.7x WRITE amplification (605 MB vs 164):
// interleaved 4B/stride-20B stores from desynced role-waves never complete a
// cache line -> partial-line evict + RFO refetch. Fix: each role writes a
// plane ws[s][b][t] it fully owns; with CHUNK=16, each lane emits one full
// 64B line per chunk (4x float4). A memory-bound transpose pass assembles
// the AoS output (contiguous 80B per lane both ways). Zero barriers, zero
// cross-role traffic. Runtime fallback to R5 direct stores if ws too small.
// All state-update arithmetic verbatim from the verified R5 kernel.

#define NB 4096
#define NT 2048
#define CHUNK 16
#define NCHUNK (NT / CHUNK)  // 128
#define BT ((size_t)NB * (size_t)NT)

#define L2E10 14.4269504089f  // 10*log2(e)  (hv(x) = sigmoid(10x))
#define L2E    1.44269504089f

__device__ __forceinline__ float rcpf(float x) { return __builtin_amdgcn_rcpf(x); }
__device__ __forceinline__ float ex2(float a)  { return __builtin_amdgcn_exp2f(a); }
__device__ __forceinline__ float ex2c(float a) { return __builtin_amdgcn_exp2f(fminf(a, 80.0f)); }
__device__ __forceinline__ float clip1e5(float x) {
    return __builtin_amdgcn_fmed3f(x, -100000.0f, 100000.0f);
}

__global__ __launch_bounds__(256, 1)
void prnn_roles(const float* __restrict__ inp, const float* __restrict__ theta,
                float* __restrict__ out, float* __restrict__ wsp, int use_ws) {
    const int lane = threadIdx.x & 63;
    const int role = threadIdx.x >> 6;
    const int b = blockIdx.x * 64 + lane;

    // ---- theta (uniform); each role uses a subset, rest DCE'd ----
    const float f_     = theta[0] * 0.1f;
    const float smax_  = theta[1] * 1950.0f;
    const float qmax_  = theta[2] * 50.0f;
    const float ddf_   = theta[3] * 5.0f;
    const float tmin_  = theta[4] * -3.0f;
    const float tmax_  = theta[5] * 3.0f;
    const float Kc_    = theta[6] * 0.5f;
    const float SCmax_ = theta[7] * 1.5f;
    const float spmax_ = theta[8] * 1950.0f;
    const float qpmax_ = theta[9] * 40.0f;
    const float kp     = theta[10];
    const float sgmax_ = theta[11] * 1950.0f;
    const float qgmax_ = theta[12] * 40.0f;
    const float Kl_    = theta[13] * 0.5f;
    const float Kn_    = theta[14] * 0.5f;

    const float inv_smax = rcpf(smax_);
    const float KcDc  = Kc_ * 0.849932f;          // Kc_ * 0.986*0.862
    const float c_sn  = -L2E10 * tmin_;
    const float c_m   =  L2E10 * tmax_;
    const float c_dd  = -ddf_ * tmax_;
    const float c_sc1 =  L2E10 * SCmax_ * 1.4f;
    const float c_sc0 =  L2E10 * SCmax_ * 0.6f;
    const float c_2p  =  L2E10 * spmax_;
    const float c_3s  =  L2E10 * smax_;
    const float c_4s  =  L2E10 * sgmax_;
    const float fE    = f_ * L2E;
    const float c_E2  = -fE * spmax_;
    const float c_E3  = -fE * smax_;
    const float c_E4  = -fE * sgmax_;

    const float* ip = inp + (size_t)b * (NT * 3);
    float*       op = out + (size_t)b * (NT * 5);
    float* wbase = use_ws ? wsp : out;   // avoid null arith when no ws

    // plane store: one full 64B line per chunk per lane
    auto plane_store = [&](float* plane, const float* ob, int c) {
        float4* d = (float4*)(plane + (size_t)c * CHUNK);
        const float4* s = (const float4*)ob;
        #pragma unroll
        for (int i = 0; i < CHUNK / 4; ++i) d[i] = s[i];
    };

    if (role == 0) {
        // ---- s0 ----
        float s0 = 0.f;
        float bA[CHUNK * 3], bB[CHUNK * 3];
        float* w0 = wbase + 0 * BT + (size_t)b * NT;
        auto pf = [&](float* d, int c) {
            const float4* s = (const float4*)(ip + (size_t)c * (CHUNK * 3));
            #pragma unroll
            for (int i = 0; i < (CHUNK * 3) / 4; ++i) ((float4*)d)[i] = s[i];
        };
        auto cw = [&](const float* d, int c) {
            float ob[CHUNK];
            #pragma unroll
            for (int i = 0; i < CHUNK; ++i) {
                const float p  = d[i * 3 + 0];
                const float dl = d[i * 3 + 2];
                const float day = rcpf(1.0f + ex2(fmaf(-L2E10, dl, 7.21347520f)));
                const float da  = 1.0f + ex2(fmaf(-L2E10, p, L2E));
                const float lai   = fmaf(0.328f, day, 0.15f);
                const float kcf   = fmaf(0.6f, day, 0.4f);
                const float kterm = KcDc * kcf * lai;
                const float zday  = fmaf(c_sc1, day, c_sc0);
                const float e0  = ex2(-L2E10 * s0);
                const float esc = ex2(fmaf(-L2E10, s0, zday));
                const float d0  = 1.0f + e0;
                const float dsc = 1.0f + esc;
                const float Rp  = rcpf(da * d0 * dsc);
                const float pintc = Rp * fmaf(d0 * esc, kterm, p);
                s0 += clip1e5(pintc);
                ob[i] = s0;
            }
            if (use_ws) plane_store(w0, ob, c);
            else {
                #pragma unroll
                for (int i = 0; i < CHUNK; ++i) op[(c * CHUNK + i) * 5 + 0] = ob[i];
            }
        };
        pf(bA, 0);
        for (int c = 0; c < NCHUNK; c += 2) {
            pf(bB, c + 1);
            cw(bA, c);
            if (c + 2 < NCHUNK) pf(bA, c + 2);
            cw(bB, c + 1);
        }
    } else if (role == 1) {
        // ---- s1 + s3 (critical role) ----
        float s1 = 0.f, s3 = 0.f;
        float bA[CHUNK * 3], bB[CHUNK * 3];
        float* w1 = wbase + 1 * BT + (size_t)b * NT;
        float* w3 = wbase + 3 * BT + (size_t)b * NT;
        auto pf = [&](float* d, int c) {
            const float4* s = (const float4*)(ip + (size_t)c * (CHUNK * 3));
            #pragma unroll
            for (int i = 0; i < (CHUNK * 3) / 4; ++i) ((float4*)d)[i] = s[i];
        };
        auto cw = [&](const float* d, int c) {
            float ob1[CHUNK], ob3[CHUNK];
            #pragma unroll
            for (int i = 0; i < CHUNK; ++i) {
                const float p  = d[i * 3 + 0];
                const float tm = d[i * 3 + 1];
                const float dl = d[i * 3 + 2];
                const float A1 = tm + 237.3f;
                const float A2 = tm + 273.2f;
                const float q  = rcpf(A1 * A2);
                const float pe = 436.98672f * dl * ex2(24.958624f * tm * (q * A2)) * (q * A1);
                const float psnow = rcpf(1.0f + ex2(fmaf(L2E10, tm, c_sn))) * p;
                const float dm = 1.0f + ex2(fmaf(-L2E10, tm, c_m));
                const float prain = p - psnow;
                const float e1 = ex2(-L2E10 * s1);
                const float melt = rcpf(dm * (1.0f + e1))
                                   * fminf(s1, fmaf(ddf_, tm, c_dd));
                const float e3  = ex2(-L2E10 * s3);
                const float e3s = ex2c(fmaf(-L2E10, s3, c_3s));
                const float R3  = rcpf((1.0f + e3) * (1.0f + e3s));
                const float E3  = ex2(fmaf(fE, s3, c_E3));
                const float t_et = pe * fmaf(e3s * s3, inv_smax, 1.0f);
                const float t_qs = qmax_ * fmaf(e3s, E3, 1.0f);
                const float outflux = R3 * (t_et + t_qs + (s3 - smax_));
                const float ds3 = prain + melt - outflux;
                s1 += clip1e5(psnow - melt);
                s3 += clip1e5(ds3);
                ob1[i] = s1;
                ob3[i] = s3;
            }
            if (use_ws) { plane_store(w1, ob1, c); plane_store(w3, ob3, c); }
            else {
                #pragma unroll
                for (int i = 0; i < CHUNK; ++i) {
                    op[(c * CHUNK + i) * 5 + 1] = ob1[i];
                    op[(c * CHUNK + i) * 5 + 3] = ob3[i];
                }
            }
        };
        pf(bA, 0);
        for (int c = 0; c < NCHUNK; c += 2) {
            pf(bB, c + 1);
            cw(bA, c);
            if (c + 2 < NCHUNK) pf(bA, c + 2);
            cw(bB, c + 1);
        }
    } else if (role == 2) {
        // ---- s2 ----
        float s2 = 0.f;
        float pA[CHUNK], pB[CHUNK];
        float* w2 = wbase + 2 * BT + (size_t)b * NT;
        auto pf = [&](float* P, int c) {
            #pragma unroll
            for (int i = 0; i < CHUNK; ++i) P[i] = ip[(c * CHUNK + i) * 3 + 0];
        };
        auto cw = [&](const float* P, int c) {
            float ob[CHUNK];
            #pragma unroll
            for (int i = 0; i < CHUNK; ++i) {
                const float p = P[i];
                const float e2  = ex2(-L2E10 * s2);
                const float e2p = ex2c(fmaf(-L2E10, s2, c_2p));
                const float R2  = rcpf((1.0f + e2) * (1.0f + e2p));
                const float E2  = ex2(fmaf(fE, s2, c_E2));
                const float qpref = R2 * fmaf(e2p * E2, kp * p, qpmax_);
                s2 += clip1e5(qpref);
                ob[i] = s2;
            }
            if (use_ws) plane_store(w2, ob, c);
            else {
                #pragma unroll
                for (int i = 0; i < CHUNK; ++i) op[(c * CHUNK + i) * 5 + 2] = ob[i];
            }
        };
        pf(pA, 0);
        for (int c = 0; c < NCHUNK; c += 2) {
            pf(pB, c + 1);
            cw(pA, c);
            if (c + 2 < NCHUNK) pf(pA, c + 2);
            cw(pB, c + 1);
        }
    } else {
        // ---- s4 ----
        float s4 = 0.f;
        float pA[CHUNK], pB[CHUNK];
        float* w4 = wbase + 4 * BT + (size_t)b * NT;
        auto pf = [&](float* P, int c) {
            #pragma unroll
            for (int i = 0; i < CHUNK; ++i) P[i] = ip[(c * CHUNK + i) * 3 + 0];
        };
        auto cw = [&](const float* P, int c) {
            float ob[CHUNK];
            #pragma unroll
            for (int i = 0; i < CHUNK; ++i) {
                const float p = P[i];
                const float e4  = ex2(-L2E10 * s4);
                const float e4s = ex2c(fmaf(-L2E10, s4, c_4s));
                const float R4  = rcpf((1.0f + e4) * (1.0f + e4s));
                const float E4  = ex2(fmaf(fE, s4, c_E4));
                const float pl  = p * fmaf(p, Kn_, Kl_);
                const float qslow = R4 * fmaf(e4s * E4, pl, qgmax_);
                s4 += clip1e5(qslow);
                ob[i] = s4;
            }
            if (use_ws) plane_store(w4, ob, c);
            else {
                #pragma unroll
                for (int i = 0; i < CHUNK; ++i) op[(c * CHUNK + i) * 5 + 4] = ob[i];
            }
        };
        pf(pA, 0);
        for (int c = 0; c < NCHUNK; c += 2) {
            pf(pB, c + 1);
            cw(pA, c);
            if (c + 2 < NCHUNK) pf(pA, c + 2);
            cw(pB, c + 1);
        }
    }
}

// ---- SoA planes -> AoS out. One thread per 4 timesteps of one chain. ----
// Reads: 16B/lane/plane, consecutive lanes contiguous. Writes: 80B/lane
// contiguous. Pure streaming, ~336 MB total.
__global__ __launch_bounds__(256)
void tx_kernel(const float* __restrict__ wsp, float* __restrict__ out) {
    const size_t idx = (size_t)blockIdx.x * 256 + threadIdx.x;  // BT/4 threads
    const size_t b  = idx / (NT / 4);
    const size_t t0 = (idx % (NT / 4)) * 4;
    const float* base = wsp + b * NT + t0;
    const float4 v0 = *(const float4*)(base + 0 * BT);
    const float4 v1 = *(const float4*)(base + 1 * BT);
    const float4 v2 = *(const float4*)(base + 2 * BT);
    const float4 v3 = *(const float4*)(base + 3 * BT);
    const float4 v4 = *(const float4*)(base + 4 * BT);
    float4* o = (float4*)(out + (b * NT + t0) * 5);
    o[0] = make_float4(v0.x, v1.x, v2.x, v3.x);
    o[1] = make_float4(v4.x, v0.y, v1.y, v2.y);
    o[2] = make_float4(v3.y, v4.y, v0.z, v1.z);
    o[3] = make_float4(v2.z, v3.z, v4.z, v0.w);
    o[4] = make_float4(v1.w, v2.w, v3.w, v4.w);
}

extern "C" void kernel_launch(void* const* d_in, const int* in_sizes, int n_in,
                              void* d_out, int out_size, void* d_ws, size_t ws_size,
                              hipStream_t stream) {
    const float* inp   = (const float*)d_in[0];
    const float* theta = (const float*)d_in[1];
    float* out = (float*)d_out;
    float* wsp = (float*)d_ws;
    const int use_ws = (wsp != nullptr && ws_size >= 5 * sizeof(float) * BT) ? 1 : 0;
    prnn_roles<<<NB / 64, 256, 0, stream>>>(inp, theta, out, wsp, use_ws);
    if (use_ws)
        tx_kernel<<<(int)(BT / 4 / 256), 256, 0, stream>>>(wsp, out);
}